// Round 1
// baseline (880.699 us; speedup 1.0000x reference)
//
#include <hip/hip_runtime.h>

#define NN 50000
#define NE 800000
#define DD 128

// ---------------- GEMM: h[n][o] = sum_k seq[n][k] * W[o][k] ----------------
// W staged in LDS transposed with additive swizzle: element W[o][k] stored at
// WT[k*128 + ((o+k)&127)].  Write side (consecutive k, fixed o) -> consecutive
// banks; read side (consecutive o, fixed k) -> consecutive banks. Conflict-free.
__global__ __launch_bounds__(256) void gemm_kernel(const float* __restrict__ seq,
                                                   const float* __restrict__ W,
                                                   float* __restrict__ h) {
    __shared__ float WT[128 * 128];   // 64 KB
    __shared__ float srow[2][128];

    for (int i = threadIdx.x; i < 128 * 128; i += 256) {
        int o = i >> 7, k = i & 127;
        WT[k * 128 + ((o + k) & 127)] = W[i];
    }
    __syncthreads();

    const int o    = threadIdx.x & 127;
    const int rsub = threadIdx.x >> 7;          // 0 or 1
    const int base = blockIdx.x * 64;           // 64 rows per block

    for (int r0 = 0; r0 < 64; r0 += 2) {
        int n0 = base + r0;
        // stage two seq rows
        {
            int r  = threadIdx.x >> 7;
            int kk = threadIdx.x & 127;
            int n  = n0 + r;
            srow[r][kk] = (n < NN) ? seq[(size_t)n * DD + kk] : 0.0f;
        }
        __syncthreads();
        float acc = 0.0f;
#pragma unroll
        for (int k = 0; k < 128; ++k)
            acc = fmaf(srow[rsub][k], WT[k * 128 + ((o + k) & 127)], acc);
        int n = n0 + rsub;
        if (n < NN) h[(size_t)n * DD + o] = acc;
        __syncthreads();
    }
}

// ---------------- Scatter: out[row] += val * h[col], one wave per edge ------
__global__ __launch_bounds__(256) void scatter_kernel(const float* __restrict__ h,
                                                      const int* __restrict__ erow,
                                                      const int* __restrict__ ecol,
                                                      const float* __restrict__ eval,
                                                      float* __restrict__ out) {
    const int lane   = threadIdx.x & 63;
    const int wave   = (blockIdx.x * blockDim.x + threadIdx.x) >> 6;
    const int nwaves = (gridDim.x * blockDim.x) >> 6;

    for (int e = wave; e < NE; e += nwaves) {
        int   r = erow[e];
        int   c = ecol[e];
        float v = eval[e];
        float2 hv = *(const float2*)&h[(size_t)c * DD + lane * 2];
        float* dst = &out[(size_t)r * DD + lane * 2];
        unsafeAtomicAdd(dst,     hv.x * v);
        unsafeAtomicAdd(dst + 1, hv.y * v);
    }
}

// ---------------- Epilogue: out = relu(out + b), in place, float4 ----------
__global__ __launch_bounds__(256) void epilogue_kernel(float* __restrict__ out,
                                                       const float* __restrict__ b) {
    const float4* b4 = (const float4*)b;
    const int total4 = NN * DD / 4;
    int i = blockIdx.x * blockDim.x + threadIdx.x;
    for (; i < total4; i += gridDim.x * blockDim.x) {
        float4 x = ((float4*)out)[i];
        float4 bb = b4[i & 31];
        x.x = fmaxf(x.x + bb.x, 0.0f);
        x.y = fmaxf(x.y + bb.y, 0.0f);
        x.z = fmaxf(x.z + bb.z, 0.0f);
        x.w = fmaxf(x.w + bb.w, 0.0f);
        ((float4*)out)[i] = x;
    }
}

extern "C" void kernel_launch(void* const* d_in, const int* in_sizes, int n_in,
                              void* d_out, int out_size, void* d_ws, size_t ws_size,
                              hipStream_t stream) {
    const float* seq  = (const float*)d_in[0];
    const float* W    = (const float*)d_in[1];
    const float* b    = (const float*)d_in[2];
    const int*   erow = (const int*)d_in[3];
    const int*   ecol = (const int*)d_in[4];
    const float* eval = (const float*)d_in[5];
    float* out = (float*)d_out;
    float* h   = (float*)d_ws;   // needs NN*DD*4 = 25.6 MB of scratch

    // accumulator must start at zero every launch (harness doesn't re-poison)
    hipMemsetAsync(out, 0, (size_t)out_size * sizeof(float), stream);

    gemm_kernel<<<(NN + 63) / 64, 256, 0, stream>>>(seq, W, h);
    scatter_kernel<<<4096, 256, 0, stream>>>(h, erow, ecol, eval, out);
    epilogue_kernel<<<2048, 256, 0, stream>>>(out, b);
}

// Round 2
// 230.494 us; speedup vs baseline: 3.8209x; 3.8209x over previous
//
#include <hip/hip_runtime.h>

#define NN 50000
#define NE 800000
#define DD 128
#define NBLK 196            // ceil(NN/256)

// ---------------- ws layout (float/int units) ----------------
#define OFF_H      0              // NN*DD floats
#define OFF_WT     6400000        // 128*128 floats (W transposed [k][o])
#define OFF_CNT    6416384        // NN ints
#define OFF_START  6466560        // NN ints (becomes end[] after fill)
#define OFF_BSUM   6516736        // 256 ints
#define OFF_BOFF   6516992        // 256 ints
#define OFF_ECOL2  6517248        // NE ints
#define OFF_EVAL2  7317248        // NE floats
#define WS_FULL_FLOATS 8117248    // 32.47 MB needed for CSR path

// ============ W transpose: WT[k][o] = W[o][k], one block ============
__global__ __launch_bounds__(256) void wt_kernel(const float* __restrict__ W,
                                                 float* __restrict__ WT) {
    __shared__ float Ws[128 * 129];   // pad 1 float: conflict-free both sides
    for (int i = threadIdx.x; i < 128 * 128; i += 256) {
        int o = i >> 7, k = i & 127;
        Ws[o * 129 + k] = W[i];
    }
    __syncthreads();
    for (int j = threadIdx.x; j < 128 * 128; j += 256) {
        int k = j >> 7, o = j & 127;
        WT[j] = Ws[o * 129 + k];
    }
}

// ============ GEMM: h = seq @ W^T, register-tiled 4x4 ============
// Block: 256 threads, 32 rows x 128 cols. LDS: As 16KB + Bs 64KB = 80KB (2 blk/CU).
// Bs holds WT[k][o] float4-XOR-swizzled: float4 (k, o4) at [k*32 + (o4 ^ (k&31))]
// -> read (fixed k, o4=ct varies) is a permutation: conflict-free b128.
__global__ __launch_bounds__(256) void gemm_kernel(const float* __restrict__ seq,
                                                   const float* __restrict__ WT,
                                                   float* __restrict__ h) {
    __shared__ float As[32 * 128];
    __shared__ float Bs[128 * 128];
    float4* As4 = (float4*)As;
    float4* Bs4 = (float4*)Bs;

    const float4* wt4 = (const float4*)WT;
    for (int i4 = threadIdx.x; i4 < 4096; i4 += 256) {
        int k = i4 >> 5, o4 = i4 & 31;
        Bs4[k * 32 + (o4 ^ (k & 31))] = wt4[i4];
    }
    const int base = blockIdx.x * 32;
    const float4* s4 = (const float4*)seq;
    for (int i4 = threadIdx.x; i4 < 32 * 32; i4 += 256) {
        int r = i4 >> 5, k4 = i4 & 31;
        int n = base + r;
        float4 v = make_float4(0.f, 0.f, 0.f, 0.f);
        if (n < NN) v = s4[(size_t)n * 32 + k4];
        As4[i4] = v;
    }
    __syncthreads();

    const int ct = threadIdx.x & 31;   // col group: cols ct*4..ct*4+3
    const int rt = threadIdx.x >> 5;   // row group: rows rt*4..rt*4+3
    float acc[4][4] = {};

#pragma unroll 4
    for (int k0 = 0; k0 < 128; k0 += 4) {
        const int k4 = k0 >> 2;
        float4 av[4], bv[4];
#pragma unroll
        for (int j = 0; j < 4; ++j) av[j] = As4[(rt * 4 + j) * 32 + k4];
#pragma unroll
        for (int j = 0; j < 4; ++j) bv[j] = Bs4[(k0 + j) * 32 + (ct ^ ((k0 + j) & 31))];
        const float* ap = (const float*)av;
        const float* bp = (const float*)bv;
#pragma unroll
        for (int kk = 0; kk < 4; ++kk)
#pragma unroll
            for (int r = 0; r < 4; ++r)
#pragma unroll
                for (int c = 0; c < 4; ++c)
                    acc[r][c] = fmaf(ap[r * 4 + kk], bp[kk * 4 + c], acc[r][c]);
    }

#pragma unroll
    for (int r = 0; r < 4; ++r) {
        int n = base + rt * 4 + r;
        if (n < NN)
            ((float4*)h)[(size_t)n * 32 + ct] =
                make_float4(acc[r][0], acc[r][1], acc[r][2], acc[r][3]);
    }
}

// ============ CSR build ============
__global__ __launch_bounds__(256) void hist_kernel(const int* __restrict__ erow,
                                                   int* __restrict__ cnt) {
    int e = blockIdx.x * 256 + threadIdx.x;
    if (e < NE) atomicAdd(&cnt[erow[e]], 1);
}

__global__ __launch_bounds__(256) void scan_partial(const int* __restrict__ cnt,
                                                    int* __restrict__ bsum) {
    int i = blockIdx.x * 256 + threadIdx.x;
    int x = (i < NN) ? cnt[i] : 0;
#pragma unroll
    for (int off = 32; off > 0; off >>= 1) x += __shfl_down(x, off);
    __shared__ int wsum[4];
    if ((threadIdx.x & 63) == 0) wsum[threadIdx.x >> 6] = x;
    __syncthreads();
    if (threadIdx.x == 0) bsum[blockIdx.x] = wsum[0] + wsum[1] + wsum[2] + wsum[3];
}

__global__ __launch_bounds__(256) void scan_bsum(const int* __restrict__ bsum,
                                                 int* __restrict__ boff) {
    __shared__ int t[256];
    int x = (threadIdx.x < NBLK) ? bsum[threadIdx.x] : 0;
    t[threadIdx.x] = x;
    __syncthreads();
    for (int off = 1; off < 256; off <<= 1) {
        int y = (threadIdx.x >= off) ? t[threadIdx.x - off] : 0;
        __syncthreads();
        t[threadIdx.x] += y;
        __syncthreads();
    }
    boff[threadIdx.x] = t[threadIdx.x] - x;   // exclusive
}

__global__ __launch_bounds__(256) void scan_final(const int* __restrict__ cnt,
                                                  const int* __restrict__ boff,
                                                  int* __restrict__ start) {
    __shared__ int t[256];
    int i = blockIdx.x * 256 + threadIdx.x;
    int x = (i < NN) ? cnt[i] : 0;
    t[threadIdx.x] = x;
    __syncthreads();
    for (int off = 1; off < 256; off <<= 1) {
        int y = (threadIdx.x >= off) ? t[threadIdx.x - off] : 0;
        __syncthreads();
        t[threadIdx.x] += y;
        __syncthreads();
    }
    if (i < NN) start[i] = t[threadIdx.x] - x + boff[blockIdx.x];
}

__global__ __launch_bounds__(256) void fill_kernel(const int* __restrict__ erow,
                                                   const int* __restrict__ ecol,
                                                   const float* __restrict__ eval,
                                                   int* __restrict__ start,
                                                   int* __restrict__ ecol2,
                                                   float* __restrict__ eval2) {
    int e = blockIdx.x * 256 + threadIdx.x;
    if (e < NE) {
        int r = erow[e];
        int pos = atomicAdd(&start[r], 1);   // start[] becomes end[]
        ecol2[pos] = ecol[e];
        eval2[pos] = eval[e];
    }
}

// ============ Gather: one wave per row, fused bias+relu ============
__global__ __launch_bounds__(256) void gather_kernel(const float* __restrict__ h,
                                                     const int* __restrict__ end,
                                                     const int* __restrict__ ecol2,
                                                     const float* __restrict__ eval2,
                                                     const float* __restrict__ b,
                                                     float* __restrict__ out) {
    const int row  = blockIdx.x * 4 + (threadIdx.x >> 6);
    const int lane = threadIdx.x & 63;
    const int begin = (row == 0) ? 0 : end[row - 1];
    const int e1 = end[row];
    float ax = 0.f, ay = 0.f;
    for (int e = begin; e < e1; ++e) {
        int   c = ecol2[e];
        float v = eval2[e];
        float2 hv = *(const float2*)&h[(size_t)c * DD + lane * 2];
        ax = fmaf(v, hv.x, ax);
        ay = fmaf(v, hv.y, ay);
    }
    float2 bb = *(const float2*)&b[lane * 2];
    float2 o2 = make_float2(fmaxf(ax + bb.x, 0.f), fmaxf(ay + bb.y, 0.f));
    *(float2*)&out[(size_t)row * DD + lane * 2] = o2;
}

// ============ Fallback (ws too small): atomic scatter path ============
__global__ __launch_bounds__(256) void scatter_kernel(const float* __restrict__ h,
                                                      const int* __restrict__ erow,
                                                      const int* __restrict__ ecol,
                                                      const float* __restrict__ eval,
                                                      float* __restrict__ out) {
    const int lane   = threadIdx.x & 63;
    const int wave   = (blockIdx.x * blockDim.x + threadIdx.x) >> 6;
    const int nwaves = (gridDim.x * blockDim.x) >> 6;
    for (int e = wave; e < NE; e += nwaves) {
        int   r = erow[e];
        int   c = ecol[e];
        float v = eval[e];
        float2 hv = *(const float2*)&h[(size_t)c * DD + lane * 2];
        float* dst = &out[(size_t)r * DD + lane * 2];
        unsafeAtomicAdd(dst,     hv.x * v);
        unsafeAtomicAdd(dst + 1, hv.y * v);
    }
}

__global__ __launch_bounds__(256) void epilogue_kernel(float* __restrict__ out,
                                                       const float* __restrict__ b) {
    const float4* b4 = (const float4*)b;
    const int total4 = NN * DD / 4;
    int i = blockIdx.x * blockDim.x + threadIdx.x;
    for (; i < total4; i += gridDim.x * blockDim.x) {
        float4 x = ((float4*)out)[i];
        float4 bb = b4[i & 31];
        x.x = fmaxf(x.x + bb.x, 0.0f);
        x.y = fmaxf(x.y + bb.y, 0.0f);
        x.z = fmaxf(x.z + bb.z, 0.0f);
        x.w = fmaxf(x.w + bb.w, 0.0f);
        ((float4*)out)[i] = x;
    }
}

extern "C" void kernel_launch(void* const* d_in, const int* in_sizes, int n_in,
                              void* d_out, int out_size, void* d_ws, size_t ws_size,
                              hipStream_t stream) {
    const float* seq  = (const float*)d_in[0];
    const float* W    = (const float*)d_in[1];
    const float* b    = (const float*)d_in[2];
    const int*   erow = (const int*)d_in[3];
    const int*   ecol = (const int*)d_in[4];
    const float* eval = (const float*)d_in[5];
    float* out = (float*)d_out;

    float* wsf = (float*)d_ws;
    float* h     = wsf + OFF_H;
    float* WT    = wsf + OFF_WT;
    int*   cnt   = (int*)(wsf + OFF_CNT);
    int*   start = (int*)(wsf + OFF_START);
    int*   bsum  = (int*)(wsf + OFF_BSUM);
    int*   boff  = (int*)(wsf + OFF_BOFF);
    int*   ecol2 = (int*)(wsf + OFF_ECOL2);
    float* eval2 = wsf + OFF_EVAL2;

    wt_kernel<<<1, 256, 0, stream>>>(W, WT);
    gemm_kernel<<<(NN + 31) / 32, 256, 0, stream>>>(seq, WT, h);

    if (ws_size >= (size_t)WS_FULL_FLOATS * sizeof(float)) {
        // CSR path: no float atomics anywhere
        hipMemsetAsync(cnt, 0, NN * sizeof(int), stream);
        hist_kernel<<<(NE + 255) / 256, 256, 0, stream>>>(erow, cnt);
        scan_partial<<<NBLK, 256, 0, stream>>>(cnt, bsum);
        scan_bsum<<<1, 256, 0, stream>>>(bsum, boff);
        scan_final<<<NBLK, 256, 0, stream>>>(cnt, boff, start);
        fill_kernel<<<(NE + 255) / 256, 256, 0, stream>>>(erow, ecol, eval,
                                                          start, ecol2, eval2);
        gather_kernel<<<NN / 4, 256, 0, stream>>>(h, start, ecol2, eval2, b, out);
    } else {
        // fallback: atomic scatter (round-1 behavior)
        hipMemsetAsync(out, 0, (size_t)out_size * sizeof(float), stream);
        scatter_kernel<<<4096, 256, 0, stream>>>(h, erow, ecol, eval, out);
        epilogue_kernel<<<2048, 256, 0, stream>>>(out, b);
    }
}

// Round 3
// 177.117 us; speedup vs baseline: 4.9724x; 1.3014x over previous
//
#include <hip/hip_runtime.h>

#define NN 50000
#define NE 800000
#define DD 128
#define NBLK 196            // ceil(NN/256)

// ---------------- ws layout (float units) ----------------
#define OFF_H      0              // NN*DD/2 floats (h in bf16)
#define OFF_WT     3200000        // 128*128 floats (W transposed [k][o], fp32)
#define OFF_CNT    3216384        // NN ints
#define OFF_START  3266384        // NN ints (becomes end[] after fill)
#define OFF_BSUM   3316384        // 256 ints
#define OFF_BOFF   3316640        // 256 ints
#define OFF_EPACK  3316896        // NE uint2 = 2*NE floats
#define WS_FULL_FLOATS 4916896    // ~19.7 MB needed for CSR path

static __device__ __forceinline__ unsigned short f2bf(float x) {
    unsigned int u = __float_as_uint(x);
    unsigned int r = (u + 0x7fffu + ((u >> 16) & 1u)) >> 16;  // RNE
    return (unsigned short)r;
}

// ============ W transpose: WT[k][o] = W[o][k], one block ============
__global__ __launch_bounds__(256) void wt_kernel(const float* __restrict__ W,
                                                 float* __restrict__ WT) {
    __shared__ float Ws[128 * 129];
    for (int i = threadIdx.x; i < 128 * 128; i += 256) {
        int o = i >> 7, k = i & 127;
        Ws[o * 129 + k] = W[i];
    }
    __syncthreads();
    for (int j = threadIdx.x; j < 128 * 128; j += 256) {
        int k = j >> 7, o = j & 127;
        WT[j] = Ws[o * 129 + k];
    }
}

// ============ GEMM: h = seq @ W^T (fp32 math, bf16 store) ============
__global__ __launch_bounds__(256) void gemm_kernel(const float* __restrict__ seq,
                                                   const float* __restrict__ WT,
                                                   unsigned short* __restrict__ h) {
    __shared__ float As[32 * 128];
    __shared__ float Bs[128 * 128];
    float4* As4 = (float4*)As;
    float4* Bs4 = (float4*)Bs;

    const float4* wt4 = (const float4*)WT;
    for (int i4 = threadIdx.x; i4 < 4096; i4 += 256) {
        int k = i4 >> 5, o4 = i4 & 31;
        Bs4[k * 32 + (o4 ^ (k & 31))] = wt4[i4];
    }
    const int base = blockIdx.x * 32;
    const float4* s4 = (const float4*)seq;
    for (int i4 = threadIdx.x; i4 < 32 * 32; i4 += 256) {
        int r = i4 >> 5, k4 = i4 & 31;
        int n = base + r;
        float4 v = make_float4(0.f, 0.f, 0.f, 0.f);
        if (n < NN) v = s4[(size_t)n * 32 + k4];
        As4[i4] = v;
    }
    __syncthreads();

    const int ct = threadIdx.x & 31;
    const int rt = threadIdx.x >> 5;
    float acc[4][4] = {};

#pragma unroll 4
    for (int k0 = 0; k0 < 128; k0 += 4) {
        const int k4 = k0 >> 2;
        float4 av[4], bv[4];
#pragma unroll
        for (int j = 0; j < 4; ++j) av[j] = As4[(rt * 4 + j) * 32 + k4];
#pragma unroll
        for (int j = 0; j < 4; ++j) bv[j] = Bs4[(k0 + j) * 32 + (ct ^ ((k0 + j) & 31))];
        const float* ap = (const float*)av;
        const float* bp = (const float*)bv;
#pragma unroll
        for (int kk = 0; kk < 4; ++kk)
#pragma unroll
            for (int r = 0; r < 4; ++r)
#pragma unroll
                for (int c = 0; c < 4; ++c)
                    acc[r][c] = fmaf(ap[r * 4 + kk], bp[kk * 4 + c], acc[r][c]);
    }

#pragma unroll
    for (int r = 0; r < 4; ++r) {
        int n = base + rt * 4 + r;
        if (n < NN) {
            ushort4 o;
            o.x = f2bf(acc[r][0]); o.y = f2bf(acc[r][1]);
            o.z = f2bf(acc[r][2]); o.w = f2bf(acc[r][3]);
            *(ushort4*)&h[(size_t)n * DD + ct * 4] = o;
        }
    }
}

// ============ CSR build ============
__global__ __launch_bounds__(256) void hist_kernel(const int* __restrict__ erow,
                                                   int* __restrict__ cnt) {
    int e = blockIdx.x * 256 + threadIdx.x;
    if (e < NE) atomicAdd(&cnt[erow[e]], 1);
}

__global__ __launch_bounds__(256) void scan_partial(const int* __restrict__ cnt,
                                                    int* __restrict__ bsum) {
    int i = blockIdx.x * 256 + threadIdx.x;
    int x = (i < NN) ? cnt[i] : 0;
#pragma unroll
    for (int off = 32; off > 0; off >>= 1) x += __shfl_down(x, off);
    __shared__ int wsum[4];
    if ((threadIdx.x & 63) == 0) wsum[threadIdx.x >> 6] = x;
    __syncthreads();
    if (threadIdx.x == 0) bsum[blockIdx.x] = wsum[0] + wsum[1] + wsum[2] + wsum[3];
}

__global__ __launch_bounds__(256) void scan_bsum(const int* __restrict__ bsum,
                                                 int* __restrict__ boff) {
    __shared__ int t[256];
    int x = (threadIdx.x < NBLK) ? bsum[threadIdx.x] : 0;
    t[threadIdx.x] = x;
    __syncthreads();
    for (int off = 1; off < 256; off <<= 1) {
        int y = (threadIdx.x >= off) ? t[threadIdx.x - off] : 0;
        __syncthreads();
        t[threadIdx.x] += y;
        __syncthreads();
    }
    boff[threadIdx.x] = t[threadIdx.x] - x;   // exclusive
}

__global__ __launch_bounds__(256) void scan_final(const int* __restrict__ cnt,
                                                  const int* __restrict__ boff,
                                                  int* __restrict__ start) {
    __shared__ int t[256];
    int i = blockIdx.x * 256 + threadIdx.x;
    int x = (i < NN) ? cnt[i] : 0;
    t[threadIdx.x] = x;
    __syncthreads();
    for (int off = 1; off < 256; off <<= 1) {
        int y = (threadIdx.x >= off) ? t[threadIdx.x - off] : 0;
        __syncthreads();
        t[threadIdx.x] += y;
        __syncthreads();
    }
    if (i < NN) start[i] = t[threadIdx.x] - x + boff[blockIdx.x];
}

__global__ __launch_bounds__(256) void fill_kernel(const int* __restrict__ erow,
                                                   const int* __restrict__ ecol,
                                                   const float* __restrict__ eval,
                                                   int* __restrict__ start,
                                                   uint2* __restrict__ epack) {
    int e = blockIdx.x * 256 + threadIdx.x;
    if (e < NE) {
        int r = erow[e];
        int pos = atomicAdd(&start[r], 1);   // start[] becomes end[]
        epack[pos] = make_uint2((unsigned)ecol[e], __float_as_uint(eval[e]));
    }
}

// ============ Gather: wave per row, 4 edge slots x 16 lanes x 8 bf16 cols ====
__global__ __launch_bounds__(256) void gather_kernel(const unsigned short* __restrict__ h,
                                                     const int* __restrict__ end,
                                                     const uint2* __restrict__ epack,
                                                     const float* __restrict__ b,
                                                     float* __restrict__ out) {
    const int row  = blockIdx.x * 4 + (threadIdx.x >> 6);
    const int lane = threadIdx.x & 63;
    const int slot = lane >> 4;      // 0..3 (edge slot)
    const int sub  = lane & 15;      // cols sub*8 .. sub*8+7
    const int begin = (row == 0) ? 0 : end[row - 1];
    const int e1 = end[row];

    float acc[8] = {0.f, 0.f, 0.f, 0.f, 0.f, 0.f, 0.f, 0.f};
    const unsigned short* hp = h + sub * 8;

#define BODY(EE) do {                                                          \
        uint2 cv = epack[EE];                                                  \
        float v = __uint_as_float(cv.y);                                       \
        uint4 hv = *(const uint4*)(hp + (size_t)cv.x * DD);                    \
        unsigned int uu;                                                       \
        uu = hv.x;                                                             \
        acc[0] = fmaf(v, __uint_as_float(uu << 16),          acc[0]);          \
        acc[1] = fmaf(v, __uint_as_float(uu & 0xffff0000u),  acc[1]);          \
        uu = hv.y;                                                             \
        acc[2] = fmaf(v, __uint_as_float(uu << 16),          acc[2]);          \
        acc[3] = fmaf(v, __uint_as_float(uu & 0xffff0000u),  acc[3]);          \
        uu = hv.z;                                                             \
        acc[4] = fmaf(v, __uint_as_float(uu << 16),          acc[4]);          \
        acc[5] = fmaf(v, __uint_as_float(uu & 0xffff0000u),  acc[5]);          \
        uu = hv.w;                                                             \
        acc[6] = fmaf(v, __uint_as_float(uu << 16),          acc[6]);          \
        acc[7] = fmaf(v, __uint_as_float(uu & 0xffff0000u),  acc[7]);          \
    } while (0)

    int e = begin + slot;
    for (; e + 4 < e1; e += 8) { BODY(e); BODY(e + 4); }
    if (e < e1) BODY(e);
#undef BODY

#pragma unroll
    for (int i = 0; i < 8; ++i) {
        acc[i] += __shfl_xor(acc[i], 16);
        acc[i] += __shfl_xor(acc[i], 32);
    }

    if (slot == 0) {
        const float4* b4 = (const float4*)(b + sub * 8);
        float4 b0 = b4[0], b1 = b4[1];
        float4 o0, o1;
        o0.x = fmaxf(acc[0] + b0.x, 0.f);
        o0.y = fmaxf(acc[1] + b0.y, 0.f);
        o0.z = fmaxf(acc[2] + b0.z, 0.f);
        o0.w = fmaxf(acc[3] + b0.w, 0.f);
        o1.x = fmaxf(acc[4] + b1.x, 0.f);
        o1.y = fmaxf(acc[5] + b1.y, 0.f);
        o1.z = fmaxf(acc[6] + b1.z, 0.f);
        o1.w = fmaxf(acc[7] + b1.w, 0.f);
        float4* op = (float4*)(out + (size_t)row * DD + sub * 8);
        op[0] = o0;
        op[1] = o1;
    }
}

// ============ Fallback (ws too small): atomic scatter path ============
__global__ __launch_bounds__(256) void scatter_kernel(const unsigned short* __restrict__ h,
                                                      const int* __restrict__ erow,
                                                      const int* __restrict__ ecol,
                                                      const float* __restrict__ eval,
                                                      float* __restrict__ out) {
    const int lane   = threadIdx.x & 63;
    const int wave   = (blockIdx.x * blockDim.x + threadIdx.x) >> 6;
    const int nwaves = (gridDim.x * blockDim.x) >> 6;
    for (int e = wave; e < NE; e += nwaves) {
        int   r = erow[e];
        int   c = ecol[e];
        float v = eval[e];
        unsigned int u = *(const unsigned int*)&h[(size_t)c * DD + lane * 2];
        float* dst = &out[(size_t)r * DD + lane * 2];
        unsafeAtomicAdd(dst,     __uint_as_float(u << 16) * v);
        unsafeAtomicAdd(dst + 1, __uint_as_float(u & 0xffff0000u) * v);
    }
}

__global__ __launch_bounds__(256) void epilogue_kernel(float* __restrict__ out,
                                                       const float* __restrict__ b) {
    const float4* b4 = (const float4*)b;
    const int total4 = NN * DD / 4;
    int i = blockIdx.x * blockDim.x + threadIdx.x;
    for (; i < total4; i += gridDim.x * blockDim.x) {
        float4 x = ((float4*)out)[i];
        float4 bb = b4[i & 31];
        x.x = fmaxf(x.x + bb.x, 0.0f);
        x.y = fmaxf(x.y + bb.y, 0.0f);
        x.z = fmaxf(x.z + bb.z, 0.0f);
        x.w = fmaxf(x.w + bb.w, 0.0f);
        ((float4*)out)[i] = x;
    }
}

extern "C" void kernel_launch(void* const* d_in, const int* in_sizes, int n_in,
                              void* d_out, int out_size, void* d_ws, size_t ws_size,
                              hipStream_t stream) {
    const float* seq  = (const float*)d_in[0];
    const float* W    = (const float*)d_in[1];
    const float* b    = (const float*)d_in[2];
    const int*   erow = (const int*)d_in[3];
    const int*   ecol = (const int*)d_in[4];
    const float* eval = (const float*)d_in[5];
    float* out = (float*)d_out;

    float* wsf = (float*)d_ws;
    unsigned short* h = (unsigned short*)(wsf + OFF_H);
    float* WT    = wsf + OFF_WT;
    int*   cnt   = (int*)(wsf + OFF_CNT);
    int*   start = (int*)(wsf + OFF_START);
    int*   bsum  = (int*)(wsf + OFF_BSUM);
    int*   boff  = (int*)(wsf + OFF_BOFF);
    uint2* epack = (uint2*)(wsf + OFF_EPACK);

    wt_kernel<<<1, 256, 0, stream>>>(W, WT);
    gemm_kernel<<<(NN + 31) / 32, 256, 0, stream>>>(seq, WT, h);

    if (ws_size >= (size_t)WS_FULL_FLOATS * sizeof(float)) {
        hipMemsetAsync(cnt, 0, NN * sizeof(int), stream);
        hist_kernel<<<(NE + 255) / 256, 256, 0, stream>>>(erow, cnt);
        scan_partial<<<NBLK, 256, 0, stream>>>(cnt, bsum);
        scan_bsum<<<1, 256, 0, stream>>>(bsum, boff);
        scan_final<<<NBLK, 256, 0, stream>>>(cnt, boff, start);
        fill_kernel<<<(NE + 255) / 256, 256, 0, stream>>>(erow, ecol, eval,
                                                          start, epack);
        gather_kernel<<<NN / 4, 256, 0, stream>>>(h, start, epack, b, out);
    } else {
        hipMemsetAsync(out, 0, (size_t)out_size * sizeof(float), stream);
        scatter_kernel<<<4096, 256, 0, stream>>>(h, erow, ecol, eval, out);
        epilogue_kernel<<<2048, 256, 0, stream>>>(out, b);
    }
}

// Round 4
// 117.758 us; speedup vs baseline: 7.4789x; 1.5041x over previous
//
#include <hip/hip_runtime.h>

#define NN 50000
#define NE 800000
#define DD 128

#define BK_SHIFT 8                 // bucket = row >> 8 (256 rows per bucket)
#define NBUCK 196                  // 49999>>8 = 195 -> 196 buckets
#define CHUNK 4096
#define NCHUNK 196                 // ceil(800000/4096)

// ---------------- ws layout (float units) ----------------
#define OFF_H      0               // NN*DD/2 floats (h in bf16) = 3,200,000
#define OFF_WT     3200000         // 128*128 fp32
#define OFF_EBIN   3216384         // NE uint2 (bucket-partitioned edges)
#define OFF_EPACK  4816384         // NE uint2 (row-sorted CSR payload)
#define OFF_END    6416384         // NN ints (CSR row end offsets)
#define OFF_CNT    6466384         // NCHUNK*NBUCK ints [block*NBUCK+bucket]
#define OFF_BB     6504800         // NBUCK*NCHUNK ints [bucket*NCHUNK+block]
#define OFF_BTOT   6543216         // NBUCK ints
#define OFF_BST    6543412         // NBUCK+1 ints
#define WS_FULL_FLOATS 6543616

static __device__ __forceinline__ unsigned short f2bf(float x) {
    unsigned int u = __float_as_uint(x);
    unsigned int r = (u + 0x7fffu + ((u >> 16) & 1u)) >> 16;  // RNE
    return (unsigned short)r;
}

// ============ W transpose: WT[k][o] = W[o][k], one block ============
__global__ __launch_bounds__(256) void wt_kernel(const float* __restrict__ W,
                                                 float* __restrict__ WT) {
    __shared__ float Ws[128 * 129];
    for (int i = threadIdx.x; i < 128 * 128; i += 256) {
        int o = i >> 7, k = i & 127;
        Ws[o * 129 + k] = W[i];
    }
    __syncthreads();
    for (int j = threadIdx.x; j < 128 * 128; j += 256) {
        int k = j >> 7, o = j & 127;
        WT[j] = Ws[o * 129 + k];
    }
}

// ============ GEMM: h = seq @ W^T (fp32 math, bf16 store) ============
__global__ __launch_bounds__(256) void gemm_kernel(const float* __restrict__ seq,
                                                   const float* __restrict__ WT,
                                                   unsigned short* __restrict__ h) {
    __shared__ float As[32 * 128];
    __shared__ float Bs[128 * 128];
    float4* As4 = (float4*)As;
    float4* Bs4 = (float4*)Bs;

    const float4* wt4 = (const float4*)WT;
    for (int i4 = threadIdx.x; i4 < 4096; i4 += 256) {
        int k = i4 >> 5, o4 = i4 & 31;
        Bs4[k * 32 + (o4 ^ (k & 31))] = wt4[i4];
    }
    const int base = blockIdx.x * 32;
    const float4* s4 = (const float4*)seq;
    for (int i4 = threadIdx.x; i4 < 32 * 32; i4 += 256) {
        int r = i4 >> 5, k4 = i4 & 31;
        int n = base + r;
        float4 v = make_float4(0.f, 0.f, 0.f, 0.f);
        if (n < NN) v = s4[(size_t)n * 32 + k4];
        As4[i4] = v;
    }
    __syncthreads();

    const int ct = threadIdx.x & 31;
    const int rt = threadIdx.x >> 5;
    float acc[4][4] = {};

#pragma unroll 4
    for (int k0 = 0; k0 < 128; k0 += 4) {
        const int k4 = k0 >> 2;
        float4 av[4], bv[4];
#pragma unroll
        for (int j = 0; j < 4; ++j) av[j] = As4[(rt * 4 + j) * 32 + k4];
#pragma unroll
        for (int j = 0; j < 4; ++j) bv[j] = Bs4[(k0 + j) * 32 + (ct ^ ((k0 + j) & 31))];
        const float* ap = (const float*)av;
        const float* bp = (const float*)bv;
#pragma unroll
        for (int kk = 0; kk < 4; ++kk)
#pragma unroll
            for (int r = 0; r < 4; ++r)
#pragma unroll
                for (int c = 0; c < 4; ++c)
                    acc[r][c] = fmaf(ap[r * 4 + kk], bp[kk * 4 + c], acc[r][c]);
    }

#pragma unroll
    for (int r = 0; r < 4; ++r) {
        int n = base + rt * 4 + r;
        if (n < NN) {
            ushort4 o;
            o.x = f2bf(acc[r][0]); o.y = f2bf(acc[r][1]);
            o.z = f2bf(acc[r][2]); o.w = f2bf(acc[r][3]);
            *(ushort4*)&h[(size_t)n * DD + ct * 4] = o;
        }
    }
}

// ============ K1: per-block bucket histogram ============
__global__ __launch_bounds__(256) void bin_count(const int* __restrict__ erow,
                                                 int* __restrict__ cnt,
                                                 int* __restrict__ btot) {
    __shared__ int lh[NBUCK];
    for (int i = threadIdx.x; i < NBUCK; i += 256) lh[i] = 0;
    __syncthreads();
    const int e0 = blockIdx.x * CHUNK;
    for (int i = threadIdx.x; i < CHUNK; i += 256) {
        int e = e0 + i;
        if (e < NE) atomicAdd(&lh[erow[e] >> BK_SHIFT], 1);
    }
    __syncthreads();
    for (int i = threadIdx.x; i < NBUCK; i += 256) {
        int c = lh[i];
        cnt[blockIdx.x * NBUCK + i] = c;
        if (c) atomicAdd(&btot[i], c);
    }
}

// ============ K2a: scan bucket totals -> bucketStart (1 block) ============
__global__ __launch_bounds__(256) void scan_bstart(const int* __restrict__ btot,
                                                   int* __restrict__ bstart) {
    __shared__ int t[256];
    int x = (threadIdx.x < NBUCK) ? btot[threadIdx.x] : 0;
    t[threadIdx.x] = x;
    __syncthreads();
    for (int off = 1; off < 256; off <<= 1) {
        int y = (threadIdx.x >= off) ? t[threadIdx.x - off] : 0;
        __syncthreads();
        t[threadIdx.x] += y;
        __syncthreads();
    }
    if (threadIdx.x < NBUCK) bstart[threadIdx.x] = t[threadIdx.x] - x;  // exclusive
    if (threadIdx.x == NBUCK - 1) bstart[NBUCK] = t[threadIdx.x];       // = NE
}

// ============ K2b: per-bucket scan across blocks -> blockbase ============
// one block per bucket; thread b holds block b's count for this bucket.
__global__ __launch_bounds__(256) void blockbase_kernel(const int* __restrict__ cnt,
                                                        const int* __restrict__ bstart,
                                                        int* __restrict__ bb) {
    __shared__ int t[256];
    const int k = blockIdx.x;        // bucket
    const int b = threadIdx.x;       // block (chunk)
    int x = (b < NCHUNK) ? cnt[b * NBUCK + k] : 0;
    t[b] = x;
    __syncthreads();
    for (int off = 1; off < 256; off <<= 1) {
        int y = (b >= off) ? t[b - off] : 0;
        __syncthreads();
        t[b] += y;
        __syncthreads();
    }
    if (b < NCHUNK) bb[k * NCHUNK + b] = bstart[k] + t[b] - x;  // exclusive + base
}

// ============ K3: partition edges into bucket-ordered ebin ============
__global__ __launch_bounds__(256) void bin_scatter(const int* __restrict__ erow,
                                                   const int* __restrict__ ecol,
                                                   const float* __restrict__ eval,
                                                   const int* __restrict__ bb,
                                                   uint2* __restrict__ ebin) {
    __shared__ int lb[NBUCK];
    for (int i = threadIdx.x; i < NBUCK; i += 256)
        lb[i] = bb[i * NCHUNK + blockIdx.x];
    __syncthreads();
    const int e0 = blockIdx.x * CHUNK;
    for (int i = threadIdx.x; i < CHUNK; i += 256) {
        int e = e0 + i;
        if (e < NE) {
            int r = erow[e], c = ecol[e];
            unsigned int vb = __float_as_uint(eval[e]);
            int pos = atomicAdd(&lb[r >> BK_SHIFT], 1);
            ebin[pos] = make_uint2(((unsigned)r << 16) | (unsigned)c, vb);
        }
    }
}

// ============ K4: per-bucket CSR build + payload fill ============
__global__ __launch_bounds__(256) void csr_fill(const uint2* __restrict__ ebin,
                                                const int* __restrict__ bstart,
                                                int* __restrict__ endv,
                                                uint2* __restrict__ epack) {
    __shared__ int lh[256];     // hist, then bump
    __shared__ int lx[256];     // scan
    const int k = blockIdx.x;
    const int t = threadIdx.x;
    const int s0 = bstart[k], s1 = bstart[k + 1];
    const int r0 = k << BK_SHIFT;

    lh[t] = 0;
    __syncthreads();
    for (int e = s0 + t; e < s1; e += 256)
        atomicAdd(&lh[(ebin[e].x >> 16) & 255], 1);
    __syncthreads();

    const int myc = lh[t];
    lx[t] = myc;
    __syncthreads();
    for (int off = 1; off < 256; off <<= 1) {
        int y = (t >= off) ? lx[t - off] : 0;
        __syncthreads();
        lx[t] += y;
        __syncthreads();
    }
    const int incl = lx[t];
    const int row = r0 + t;
    if (row < NN) endv[row] = s0 + incl;
    __syncthreads();
    lh[t] = s0 + incl - myc;    // bump = global exclusive offset
    __syncthreads();

    for (int e = s0 + t; e < s1; e += 256) {
        uint2 ed = ebin[e];
        int pos = atomicAdd(&lh[(ed.x >> 16) & 255], 1);
        epack[pos] = make_uint2(ed.x & 0xffffu, ed.y);
    }
}

// ============ Gather: wave per row, 4 edge slots x 16 lanes x 8 bf16 cols ====
__global__ __launch_bounds__(256) void gather_kernel(const unsigned short* __restrict__ h,
                                                     const int* __restrict__ end,
                                                     const uint2* __restrict__ epack,
                                                     const float* __restrict__ b,
                                                     float* __restrict__ out) {
    const int row  = blockIdx.x * 4 + (threadIdx.x >> 6);
    const int lane = threadIdx.x & 63;
    const int slot = lane >> 4;      // 0..3 (edge slot)
    const int sub  = lane & 15;      // cols sub*8 .. sub*8+7
    const int begin = (row == 0) ? 0 : end[row - 1];
    const int e1 = end[row];

    float acc[8] = {0.f, 0.f, 0.f, 0.f, 0.f, 0.f, 0.f, 0.f};
    const unsigned short* hp = h + sub * 8;

#define BODY(EE) do {                                                          \
        uint2 cv = epack[EE];                                                  \
        float v = __uint_as_float(cv.y);                                       \
        uint4 hv = *(const uint4*)(hp + (size_t)cv.x * DD);                    \
        unsigned int uu;                                                       \
        uu = hv.x;                                                             \
        acc[0] = fmaf(v, __uint_as_float(uu << 16),          acc[0]);          \
        acc[1] = fmaf(v, __uint_as_float(uu & 0xffff0000u),  acc[1]);          \
        uu = hv.y;                                                             \
        acc[2] = fmaf(v, __uint_as_float(uu << 16),          acc[2]);          \
        acc[3] = fmaf(v, __uint_as_float(uu & 0xffff0000u),  acc[3]);          \
        uu = hv.z;                                                             \
        acc[4] = fmaf(v, __uint_as_float(uu << 16),          acc[4]);          \
        acc[5] = fmaf(v, __uint_as_float(uu & 0xffff0000u),  acc[5]);          \
        uu = hv.w;                                                             \
        acc[6] = fmaf(v, __uint_as_float(uu << 16),          acc[6]);          \
        acc[7] = fmaf(v, __uint_as_float(uu & 0xffff0000u),  acc[7]);          \
    } while (0)

    int e = begin + slot;
    for (; e + 4 < e1; e += 8) { BODY(e); BODY(e + 4); }
    if (e < e1) BODY(e);
#undef BODY

#pragma unroll
    for (int i = 0; i < 8; ++i) {
        acc[i] += __shfl_xor(acc[i], 16);
        acc[i] += __shfl_xor(acc[i], 32);
    }

    if (slot == 0) {
        const float4* b4 = (const float4*)(b + sub * 8);
        float4 b0 = b4[0], b1 = b4[1];
        float4 o0, o1;
        o0.x = fmaxf(acc[0] + b0.x, 0.f);
        o0.y = fmaxf(acc[1] + b0.y, 0.f);
        o0.z = fmaxf(acc[2] + b0.z, 0.f);
        o0.w = fmaxf(acc[3] + b0.w, 0.f);
        o1.x = fmaxf(acc[4] + b1.x, 0.f);
        o1.y = fmaxf(acc[5] + b1.y, 0.f);
        o1.z = fmaxf(acc[6] + b1.z, 0.f);
        o1.w = fmaxf(acc[7] + b1.w, 0.f);
        float4* op = (float4*)(out + (size_t)row * DD + sub * 8);
        op[0] = o0;
        op[1] = o1;
    }
}

// ============ Fallback (ws too small): atomic scatter path ============
__global__ __launch_bounds__(256) void scatter_kernel(const unsigned short* __restrict__ h,
                                                      const int* __restrict__ erow,
                                                      const int* __restrict__ ecol,
                                                      const float* __restrict__ eval,
                                                      float* __restrict__ out) {
    const int lane   = threadIdx.x & 63;
    const int wave   = (blockIdx.x * blockDim.x + threadIdx.x) >> 6;
    const int nwaves = (gridDim.x * blockDim.x) >> 6;
    for (int e = wave; e < NE; e += nwaves) {
        int   r = erow[e];
        int   c = ecol[e];
        float v = eval[e];
        unsigned int u = *(const unsigned int*)&h[(size_t)c * DD + lane * 2];
        float* dst = &out[(size_t)r * DD + lane * 2];
        unsafeAtomicAdd(dst,     __uint_as_float(u << 16) * v);
        unsafeAtomicAdd(dst + 1, __uint_as_float(u & 0xffff0000u) * v);
    }
}

__global__ __launch_bounds__(256) void epilogue_kernel(float* __restrict__ out,
                                                       const float* __restrict__ b) {
    const float4* b4 = (const float4*)b;
    const int total4 = NN * DD / 4;
    int i = blockIdx.x * blockDim.x + threadIdx.x;
    for (; i < total4; i += gridDim.x * blockDim.x) {
        float4 x = ((float4*)out)[i];
        float4 bb = b4[i & 31];
        x.x = fmaxf(x.x + bb.x, 0.0f);
        x.y = fmaxf(x.y + bb.y, 0.0f);
        x.z = fmaxf(x.z + bb.z, 0.0f);
        x.w = fmaxf(x.w + bb.w, 0.0f);
        ((float4*)out)[i] = x;
    }
}

extern "C" void kernel_launch(void* const* d_in, const int* in_sizes, int n_in,
                              void* d_out, int out_size, void* d_ws, size_t ws_size,
                              hipStream_t stream) {
    const float* seq  = (const float*)d_in[0];
    const float* W    = (const float*)d_in[1];
    const float* b    = (const float*)d_in[2];
    const int*   erow = (const int*)d_in[3];
    const int*   ecol = (const int*)d_in[4];
    const float* eval = (const float*)d_in[5];
    float* out = (float*)d_out;

    float* wsf = (float*)d_ws;
    unsigned short* h = (unsigned short*)(wsf + OFF_H);
    float* WT    = wsf + OFF_WT;
    uint2* ebin  = (uint2*)(wsf + OFF_EBIN);
    uint2* epack = (uint2*)(wsf + OFF_EPACK);
    int*   endv  = (int*)(wsf + OFF_END);
    int*   cnt   = (int*)(wsf + OFF_CNT);
    int*   bb    = (int*)(wsf + OFF_BB);
    int*   btot  = (int*)(wsf + OFF_BTOT);
    int*   bst   = (int*)(wsf + OFF_BST);

    wt_kernel<<<1, 256, 0, stream>>>(W, WT);
    gemm_kernel<<<(NN + 31) / 32, 256, 0, stream>>>(seq, WT, h);

    if (ws_size >= (size_t)WS_FULL_FLOATS * sizeof(float)) {
        hipMemsetAsync(btot, 0, NBUCK * sizeof(int), stream);
        bin_count<<<NCHUNK, 256, 0, stream>>>(erow, cnt, btot);
        scan_bstart<<<1, 256, 0, stream>>>(btot, bst);
        blockbase_kernel<<<NBUCK, 256, 0, stream>>>(cnt, bst, bb);
        bin_scatter<<<NCHUNK, 256, 0, stream>>>(erow, ecol, eval, bb, ebin);
        csr_fill<<<NBUCK, 256, 0, stream>>>(ebin, bst, endv, epack);
        gather_kernel<<<NN / 4, 256, 0, stream>>>(h, endv, epack, b, out);
    } else {
        hipMemsetAsync(out, 0, (size_t)out_size * sizeof(float), stream);
        scatter_kernel<<<4096, 256, 0, stream>>>(h, erow, ecol, eval, out);
        epilogue_kernel<<<2048, 256, 0, stream>>>(out, b);
    }
}

// Round 7
// 93.287 us; speedup vs baseline: 9.4408x; 1.2623x over previous
//
#include <hip/hip_runtime.h>

#define NN 50000
#define NE 800000
#define DD 128

#define BK_SHIFT 8                 // bucket = row >> 8 (256 rows per bucket)
#define NBUCK 196
#define CHUNK 4096
#define NCHUNK 196                 // ceil(800000/4096)
#define NGB 782                    // ceil(50000/64) gemm blocks

// ---------------- ws layout (float units) ----------------
#define OFF_H      0               // NN*DD bf16 = 3,200,000 floats
#define OFF_EBIN   3200000         // NE uint2
#define OFF_EPACK  4800000         // NE uint2
#define OFF_END    6400000         // NN ints
#define OFF_CNT    6450000         // NCHUNK*NBUCK ints [chunk*NBUCK+bucket]
#define OFF_BB     6488416         // NBUCK*NCHUNK ints [bucket*NCHUNK+chunk]
#define OFF_BTOT   6526832         // NBUCK ints
#define OFF_BST    6527028         // NBUCK+1 ints
#define WS_FULL_FLOATS 6527232

typedef short short8 __attribute__((ext_vector_type(8)));
typedef float f32x4 __attribute__((ext_vector_type(4)));
typedef unsigned int uint32x2 __attribute__((ext_vector_type(2)));

static __device__ __forceinline__ unsigned int f2bf(float x) {
    unsigned int u = __float_as_uint(x);
    return (u + 0x7fffu + ((u >> 16) & 1u)) >> 16;  // RNE
}

// ============ K1: fused MFMA GEMM (blocks 0..NGB-1) + bin_count (rest) =======
// GEMM: h[n][o] = sum_k seq[n][k]*W[o][k], bf16 inputs, fp32 MFMA accum.
// LDS: As 64x128 bf16 (16KB, swizzled) | Bs = W[o][k] bf16 (32KB, swizzled).
__global__ __launch_bounds__(256) void k1_gemm_bincount(
        const float* __restrict__ seq, const float* __restrict__ W,
        unsigned short* __restrict__ h,
        const int* __restrict__ erow, int* __restrict__ cnt,
        int* __restrict__ btot) {
    __shared__ uint4 lds4[3072];           // 48 KB
    char* lds = (char*)lds4;
    const int t = threadIdx.x;

    if (blockIdx.x >= NGB) {
        // ---- bin_count path ----
        int* lh = (int*)lds4;
        const int chunk = blockIdx.x - NGB;
        for (int i = t; i < NBUCK; i += 256) lh[i] = 0;
        __syncthreads();
        const int e0 = chunk * CHUNK;
        for (int i = t; i < CHUNK; i += 256) {
            int e = e0 + i;
            if (e < NE) atomicAdd(&lh[erow[e] >> BK_SHIFT], 1);
        }
        __syncthreads();
        for (int i = t; i < NBUCK; i += 256) {
            int c = lh[i];
            cnt[chunk * NBUCK + i] = c;
            if (c) atomicAdd(&btot[i], c);
        }
        return;
    }

    // ---- GEMM path ----
    const int base = blockIdx.x * 64;
#define BS_OFF 16384

    // stage Bs: W[o][k] fp32 -> bf16, swizzled. thread: o=t>>1, 64 k's
    // (16 float4 loads -> 8 uint4 LDS writes).
    {
        const int o = t >> 1, ksb = (t & 1) * 64;
        const float4* Wr = (const float4*)(W + o * 128 + ksb);
#pragma unroll
        for (int i = 0; i < 16; i += 2) {
            float4 x = Wr[i], y = Wr[i + 1];
            uint4 p;
            p.x = f2bf(x.x) | (f2bf(x.y) << 16);
            p.y = f2bf(x.z) | (f2bf(x.w) << 16);
            p.z = f2bf(y.x) | (f2bf(y.y) << 16);
            p.w = f2bf(y.z) | (f2bf(y.w) << 16);
            int byte = o * 256 + (ksb + i * 4) * 2;
            *(uint4*)(lds + BS_OFF + (byte ^ ((o & 7) << 4))) = p;
        }
    }
    // stage As: seq rows [base..base+64) fp32 -> bf16, swizzled.
    {
        const int row = t >> 2, n = base + row;
        const int c0 = (t & 3) * 4;
        const float4* Sr = (const float4*)(seq + (size_t)n * 128);
        const bool ok = (n < NN);
#pragma unroll
        for (int i = 0; i < 4; ++i) {
            int cc = c0 + i;   // 16B chunk index (8 bf16)
            float4 x = ok ? Sr[cc * 2]     : make_float4(0.f, 0.f, 0.f, 0.f);
            float4 y = ok ? Sr[cc * 2 + 1] : make_float4(0.f, 0.f, 0.f, 0.f);
            uint4 p;
            p.x = f2bf(x.x) | (f2bf(x.y) << 16);
            p.y = f2bf(x.z) | (f2bf(x.w) << 16);
            p.z = f2bf(y.x) | (f2bf(y.y) << 16);
            p.w = f2bf(y.z) | (f2bf(y.w) << 16);
            int byte = row * 256 + cc * 16;
            *(uint4*)(lds + (byte ^ ((row & 7) << 4))) = p;
        }
    }
    __syncthreads();

    const int l = t & 63, wv = t >> 6;
    const int lr = l & 15, kg = l >> 4;
    const int arow = wv * 16 + lr;
    f32x4 acc[8] = {};

#pragma unroll
    for (int ks = 0; ks < 4; ++ks) {
        const int kbyte = ks * 64 + kg * 16;
        short8 av = *(short8*)(lds + ((arow * 256 + kbyte) ^ ((arow & 7) << 4)));
#pragma unroll
        for (int c = 0; c < 8; ++c) {
            const int o = c * 16 + lr;
            short8 bv = *(short8*)(lds + BS_OFF +
                                   ((o * 256 + kbyte) ^ ((o & 7) << 4)));
            acc[c] = __builtin_amdgcn_mfma_f32_16x16x32_bf16(av, bv, acc[c], 0, 0, 0);
        }
    }

#pragma unroll
    for (int c = 0; c < 8; ++c) {
#pragma unroll
        for (int r = 0; r < 4; ++r) {
            int n = base + wv * 16 + kg * 4 + r;
            if (n < NN)
                h[(size_t)n * DD + c * 16 + lr] = (unsigned short)f2bf(acc[c][r]);
        }
    }
}

// ============ K2: merged scans -> bst, bb ============
__global__ __launch_bounds__(256) void k2_scan(const int* __restrict__ btot,
                                               const int* __restrict__ cnt,
                                               int* __restrict__ bst,
                                               int* __restrict__ bb) {
    __shared__ int tt[256];
    __shared__ int tb[256];
    const int k = blockIdx.x;
    const int t = threadIdx.x;

    int x = (t < NBUCK) ? btot[t] : 0;
    tt[t] = x;
    __syncthreads();
    for (int off = 1; off < 256; off <<= 1) {
        int y = (t >= off) ? tt[t - off] : 0;
        __syncthreads();
        tt[t] += y;
        __syncthreads();
    }
    if (k == 0) {
        if (t < NBUCK) bst[t] = tt[t] - x;          // exclusive
        if (t == NBUCK - 1) bst[NBUCK] = tt[t];     // = NE
    }
    const int kbase = (k == 0) ? 0 : tt[k - 1];

    int xb = (t < NCHUNK) ? cnt[t * NBUCK + k] : 0;
    tb[t] = xb;
    __syncthreads();
    for (int off = 1; off < 256; off <<= 1) {
        int y = (t >= off) ? tb[t - off] : 0;
        __syncthreads();
        tb[t] += y;
        __syncthreads();
    }
    if (t < NCHUNK) bb[k * NCHUNK + t] = kbase + tb[t] - xb;
}

// ============ K3: partition edges into bucket-ordered ebin ============
__global__ __launch_bounds__(256) void bin_scatter(const int* __restrict__ erow,
                                                   const int* __restrict__ ecol,
                                                   const float* __restrict__ eval,
                                                   const int* __restrict__ bb,
                                                   uint2* __restrict__ ebin) {
    __shared__ int lb[NBUCK];
    for (int i = threadIdx.x; i < NBUCK; i += 256)
        lb[i] = bb[i * NCHUNK + blockIdx.x];
    __syncthreads();
    const int e0 = blockIdx.x * CHUNK;
    for (int i = threadIdx.x; i < CHUNK; i += 256) {
        int e = e0 + i;
        if (e < NE) {
            int r = erow[e], c = ecol[e];
            unsigned int vb = __float_as_uint(eval[e]);
            int pos = atomicAdd(&lb[r >> BK_SHIFT], 1);
            ebin[pos] = make_uint2(((unsigned)r << 16) | (unsigned)c, vb);
        }
    }
}

// ============ K4: per-bucket CSR build + payload fill ============
__global__ __launch_bounds__(256) void csr_fill(const uint2* __restrict__ ebin,
                                                const int* __restrict__ bstart,
                                                int* __restrict__ endv,
                                                uint2* __restrict__ epack) {
    __shared__ int lh[256];
    __shared__ int lx[256];
    const int k = blockIdx.x;
    const int t = threadIdx.x;
    const int s0 = bstart[k], s1 = bstart[k + 1];
    const int r0 = k << BK_SHIFT;

    lh[t] = 0;
    __syncthreads();
    for (int e = s0 + t; e < s1; e += 256)
        atomicAdd(&lh[(ebin[e].x >> 16) & 255], 1);
    __syncthreads();

    const int myc = lh[t];
    lx[t] = myc;
    __syncthreads();
    for (int off = 1; off < 256; off <<= 1) {
        int y = (t >= off) ? lx[t - off] : 0;
        __syncthreads();
        lx[t] += y;
        __syncthreads();
    }
    const int incl = lx[t];
    const int row = r0 + t;
    if (row < NN) endv[row] = s0 + incl;
    __syncthreads();
    lh[t] = s0 + incl - myc;
    __syncthreads();

    for (int e = s0 + t; e < s1; e += 256) {
        uint2 ed = ebin[e];
        int pos = atomicAdd(&lh[(ed.x >> 16) & 255], 1);
        epack[pos] = make_uint2(ed.x & 0xffffu, ed.y);
    }
}

// ============ K5: gather, wave per row, 4 edge slots x 16 lanes ============
__global__ __launch_bounds__(256) void gather_kernel(const unsigned short* __restrict__ h,
                                                     const int* __restrict__ end,
                                                     const unsigned int* __restrict__ epack,
                                                     const float* __restrict__ b,
                                                     float* __restrict__ out) {
    const int row  = blockIdx.x * 4 + (threadIdx.x >> 6);
    const int lane = threadIdx.x & 63;
    const int slot = lane >> 4;
    const int sub  = lane & 15;
    const int begin = (row == 0) ? 0 : end[row - 1];
    const int e1 = end[row];

    float acc[8] = {0.f, 0.f, 0.f, 0.f, 0.f, 0.f, 0.f, 0.f};
    const unsigned short* hp = h + sub * 8;

#define BODY(EE) do {                                                          \
        uint32x2 cv = __builtin_nontemporal_load(                              \
            (const uint32x2*)(epack + (size_t)(EE) * 2));                      \
        float v = __uint_as_float(cv.y);                                       \
        uint4 hv = *(const uint4*)(hp + (size_t)cv.x * DD);                    \
        unsigned int uu;                                                       \
        uu = hv.x;                                                             \
        acc[0] = fmaf(v, __uint_as_float(uu << 16),          acc[0]);          \
        acc[1] = fmaf(v, __uint_as_float(uu & 0xffff0000u),  acc[1]);          \
        uu = hv.y;                                                             \
        acc[2] = fmaf(v, __uint_as_float(uu << 16),          acc[2]);          \
        acc[3] = fmaf(v, __uint_as_float(uu & 0xffff0000u),  acc[3]);          \
        uu = hv.z;                                                             \
        acc[4] = fmaf(v, __uint_as_float(uu << 16),          acc[4]);          \
        acc[5] = fmaf(v, __uint_as_float(uu & 0xffff0000u),  acc[5]);          \
        uu = hv.w;                                                             \
        acc[6] = fmaf(v, __uint_as_float(uu << 16),          acc[6]);          \
        acc[7] = fmaf(v, __uint_as_float(uu & 0xffff0000u),  acc[7]);          \
    } while (0)

    int e = begin + slot;
    for (; e + 4 < e1; e += 8) { BODY(e); BODY(e + 4); }
    if (e < e1) BODY(e);
#undef BODY

#pragma unroll
    for (int i = 0; i < 8; ++i) {
        acc[i] += __shfl_xor(acc[i], 16);
        acc[i] += __shfl_xor(acc[i], 32);
    }

    if (slot == 0) {
        const float4* b4 = (const float4*)(b + sub * 8);
        float4 b0 = b4[0], b1 = b4[1];
        f32x4 o0, o1;
        o0.x = fmaxf(acc[0] + b0.x, 0.f);
        o0.y = fmaxf(acc[1] + b0.y, 0.f);
        o0.z = fmaxf(acc[2] + b0.z, 0.f);
        o0.w = fmaxf(acc[3] + b0.w, 0.f);
        o1.x = fmaxf(acc[4] + b1.x, 0.f);
        o1.y = fmaxf(acc[5] + b1.y, 0.f);
        o1.z = fmaxf(acc[6] + b1.z, 0.f);
        o1.w = fmaxf(acc[7] + b1.w, 0.f);
        f32x4* op = (f32x4*)(out + (size_t)row * DD + sub * 8);
        __builtin_nontemporal_store(o0, op);
        __builtin_nontemporal_store(o1, op + 1);
    }
}

// ============ Fallback (ws too small): atomic scatter path ============
__global__ __launch_bounds__(256) void scatter_kernel(const unsigned short* __restrict__ h,
                                                      const int* __restrict__ erow,
                                                      const int* __restrict__ ecol,
                                                      const float* __restrict__ eval,
                                                      float* __restrict__ out) {
    const int lane   = threadIdx.x & 63;
    const int wave   = (blockIdx.x * blockDim.x + threadIdx.x) >> 6;
    const int nwaves = (gridDim.x * blockDim.x) >> 6;
    for (int e = wave; e < NE; e += nwaves) {
        int   r = erow[e];
        int   c = ecol[e];
        float v = eval[e];
        unsigned int u = *(const unsigned int*)&h[(size_t)c * DD + lane * 2];
        float* dst = &out[(size_t)r * DD + lane * 2];
        unsafeAtomicAdd(dst,     __uint_as_float(u << 16) * v);
        unsafeAtomicAdd(dst + 1, __uint_as_float(u & 0xffff0000u) * v);
    }
}

__global__ __launch_bounds__(256) void epilogue_kernel(float* __restrict__ out,
                                                       const float* __restrict__ b) {
    const float4* b4 = (const float4*)b;
    const int total4 = NN * DD / 4;
    int i = blockIdx.x * blockDim.x + threadIdx.x;
    for (; i < total4; i += gridDim.x * blockDim.x) {
        float4 x = ((float4*)out)[i];
        float4 bb = b4[i & 31];
        x.x = fmaxf(x.x + bb.x, 0.0f);
        x.y = fmaxf(x.y + bb.y, 0.0f);
        x.z = fmaxf(x.z + bb.z, 0.0f);
        x.w = fmaxf(x.w + bb.w, 0.0f);
        ((float4*)out)[i] = x;
    }
}

extern "C" void kernel_launch(void* const* d_in, const int* in_sizes, int n_in,
                              void* d_out, int out_size, void* d_ws, size_t ws_size,
                              hipStream_t stream) {
    const float* seq  = (const float*)d_in[0];
    const float* W    = (const float*)d_in[1];
    const float* b    = (const float*)d_in[2];
    const int*   erow = (const int*)d_in[3];
    const int*   ecol = (const int*)d_in[4];
    const float* eval = (const float*)d_in[5];
    float* out = (float*)d_out;

    float* wsf = (float*)d_ws;
    unsigned short* h = (unsigned short*)(wsf + OFF_H);
    uint2* ebin  = (uint2*)(wsf + OFF_EBIN);
    uint2* epack = (uint2*)(wsf + OFF_EPACK);
    int*   endv  = (int*)(wsf + OFF_END);
    int*   cnt   = (int*)(wsf + OFF_CNT);
    int*   bb    = (int*)(wsf + OFF_BB);
    int*   btot  = (int*)(wsf + OFF_BTOT);
    int*   bst   = (int*)(wsf + OFF_BST);

    if (ws_size >= (size_t)WS_FULL_FLOATS * sizeof(float)) {
        hipMemsetAsync(btot, 0, NBUCK * sizeof(int), stream);
        k1_gemm_bincount<<<NGB + NCHUNK, 256, 0, stream>>>(seq, W, h, erow, cnt, btot);
        k2_scan<<<NBUCK, 256, 0, stream>>>(btot, cnt, bst, bb);
        bin_scatter<<<NCHUNK, 256, 0, stream>>>(erow, ecol, eval, bb, ebin);
        csr_fill<<<NBUCK, 256, 0, stream>>>(ebin, bst, endv, epack);
        gather_kernel<<<NN / 4, 256, 0, stream>>>(h, endv, (const unsigned int*)epack, b, out);
    } else {
        k1_gemm_bincount<<<NGB, 256, 0, stream>>>(seq, W, h, erow, cnt, btot);
        hipMemsetAsync(out, 0, (size_t)out_size * sizeof(float), stream);
        scatter_kernel<<<4096, 256, 0, stream>>>(h, erow, ecol, eval, out);
        epilogue_kernel<<<2048, 256, 0, stream>>>(out, b);
    }
}

// Round 8
// 89.105 us; speedup vs baseline: 9.8839x; 1.0469x over previous
//
#include <hip/hip_runtime.h>

#define NN 50000
#define NE 800000
#define DD 128

#define BK_SHIFT 8                 // bucket = row >> 8 (256 rows per bucket)
#define NBUCK 196
#define CHUNK 4096
#define NCHUNK 196                 // ceil(800000/4096)
#define NGB 782                    // ceil(50000/64) gemm blocks
#define ECAP 8192                  // entries per bucket region (mean 4096, sigma 64)

// ---------------- ws layout (float units) ----------------
#define OFF_H      0               // NN*DD bf16 = 3,200,000 floats
#define OFF_EBIN   3200000         // NBUCK*ECAP uint2 = 3,211,264 floats
#define OFF_EPACK  6411264         // NBUCK*ECAP uint2
#define OFF_END    9622528         // NN ints
#define OFF_CUR    9672528         // NBUCK ints
#define WS_FULL_FLOATS 9672724     // ~38.7 MB

typedef short short8 __attribute__((ext_vector_type(8)));
typedef float f32x4 __attribute__((ext_vector_type(4)));
typedef unsigned int uint32x2 __attribute__((ext_vector_type(2)));

static __device__ __forceinline__ unsigned int f2bf(float x) {
    unsigned int u = __float_as_uint(x);
    return (u + 0x7fffu + ((u >> 16) & 1u)) >> 16;  // RNE
}

// ============ K1: MFMA GEMM (blocks 0..NGB-1) || bucket-scatter (rest) =======
__global__ __launch_bounds__(256) void k1_gemm_scatter(
        const float* __restrict__ seq, const float* __restrict__ W,
        unsigned short* __restrict__ h,
        const int* __restrict__ erow, const int* __restrict__ ecol,
        const float* __restrict__ eval,
        int* __restrict__ gcur, uint2* __restrict__ ebin) {
    __shared__ uint4 lds4[3072];           // 48 KB
    char* lds = (char*)lds4;
    const int t = threadIdx.x;

    if (blockIdx.x >= NGB) {
        // ---- scatter path: LDS hist -> global bump-reserve -> run writes ----
        int* lh = (int*)lds4;              // [NBUCK] count, then cursor
        const int chunk = blockIdx.x - NGB;
        for (int i = t; i < NBUCK; i += 256) lh[i] = 0;
        __syncthreads();
        const int e0 = chunk * CHUNK;
        for (int i = t; i < CHUNK; i += 256) {
            int e = e0 + i;
            if (e < NE) atomicAdd(&lh[erow[e] >> BK_SHIFT], 1);
        }
        __syncthreads();
        for (int i = t; i < NBUCK; i += 256) {
            int c = lh[i];
            lh[i] = c ? atomicAdd(&gcur[i], c) : 0;   // count -> bucket-local base
        }
        __syncthreads();
        for (int i = t; i < CHUNK; i += 256) {
            int e = e0 + i;
            if (e < NE) {
                int r = erow[e], c = ecol[e];
                unsigned int vb = __float_as_uint(eval[e]);
                int k = r >> BK_SHIFT;
                int pos = atomicAdd(&lh[k], 1);
                if (pos < ECAP)
                    ebin[(size_t)k * ECAP + pos] =
                        make_uint2(((unsigned)r << 16) | (unsigned)c, vb);
            }
        }
        return;
    }

    // ---- GEMM path: h[n][o] = sum_k seq[n][k]*W[o][k], bf16-in fp32-acc ----
    const int base = blockIdx.x * 64;
#define BS_OFF 16384

    // stage Bs: W[o][k] fp32 -> bf16, swizzled. thread: o=t>>1, 64 k's.
    {
        const int o = t >> 1, ksb = (t & 1) * 64;
        const float4* Wr = (const float4*)(W + o * 128 + ksb);
#pragma unroll
        for (int i = 0; i < 16; i += 2) {
            float4 x = Wr[i], y = Wr[i + 1];
            uint4 p;
            p.x = f2bf(x.x) | (f2bf(x.y) << 16);
            p.y = f2bf(x.z) | (f2bf(x.w) << 16);
            p.z = f2bf(y.x) | (f2bf(y.y) << 16);
            p.w = f2bf(y.z) | (f2bf(y.w) << 16);
            int byte = o * 256 + (ksb + i * 4) * 2;
            *(uint4*)(lds + BS_OFF + (byte ^ ((o & 7) << 4))) = p;
        }
    }
    // stage As: seq rows [base..base+64) fp32 -> bf16, swizzled.
    {
        const int row = t >> 2, n = base + row;
        const int c0 = (t & 3) * 4;
        const float4* Sr = (const float4*)(seq + (size_t)n * 128);
        const bool ok = (n < NN);
#pragma unroll
        for (int i = 0; i < 4; ++i) {
            int cc = c0 + i;
            float4 x = ok ? Sr[cc * 2]     : make_float4(0.f, 0.f, 0.f, 0.f);
            float4 y = ok ? Sr[cc * 2 + 1] : make_float4(0.f, 0.f, 0.f, 0.f);
            uint4 p;
            p.x = f2bf(x.x) | (f2bf(x.y) << 16);
            p.y = f2bf(x.z) | (f2bf(x.w) << 16);
            p.z = f2bf(y.x) | (f2bf(y.y) << 16);
            p.w = f2bf(y.z) | (f2bf(y.w) << 16);
            int byte = row * 256 + cc * 16;
            *(uint4*)(lds + (byte ^ ((row & 7) << 4))) = p;
        }
    }
    __syncthreads();

    const int l = t & 63, wv = t >> 6;
    const int lr = l & 15, kg = l >> 4;
    const int arow = wv * 16 + lr;
    f32x4 acc[8] = {};

#pragma unroll
    for (int ks = 0; ks < 4; ++ks) {
        const int kbyte = ks * 64 + kg * 16;
        short8 av = *(short8*)(lds + ((arow * 256 + kbyte) ^ ((arow & 7) << 4)));
#pragma unroll
        for (int c = 0; c < 8; ++c) {
            const int o = c * 16 + lr;
            short8 bv = *(short8*)(lds + BS_OFF +
                                   ((o * 256 + kbyte) ^ ((o & 7) << 4)));
            acc[c] = __builtin_amdgcn_mfma_f32_16x16x32_bf16(av, bv, acc[c], 0, 0, 0);
        }
    }

#pragma unroll
    for (int c = 0; c < 8; ++c) {
#pragma unroll
        for (int r = 0; r < 4; ++r) {
            int n = base + wv * 16 + kg * 4 + r;
            if (n < NN)
                h[(size_t)n * DD + c * 16 + lr] = (unsigned short)f2bf(acc[c][r]);
        }
    }
}

// ============ K2: per-bucket CSR build + payload fill ============
__global__ __launch_bounds__(256) void csr_fill(const uint2* __restrict__ ebin,
                                                const int* __restrict__ gcur,
                                                int* __restrict__ endv,
                                                uint2* __restrict__ epack) {
    __shared__ int lh[256];
    __shared__ int lx[256];
    const int k = blockIdx.x;
    const int t = threadIdx.x;
    const size_t s0 = (size_t)k * ECAP;
    int cnt = gcur[k];
    if (cnt > ECAP) cnt = ECAP;
    const size_t s1 = s0 + cnt;
    const int r0 = k << BK_SHIFT;

    lh[t] = 0;
    __syncthreads();
    for (size_t e = s0 + t; e < s1; e += 256)
        atomicAdd(&lh[(ebin[e].x >> 16) & 255], 1);
    __syncthreads();

    const int myc = lh[t];
    lx[t] = myc;
    __syncthreads();
    for (int off = 1; off < 256; off <<= 1) {
        int y = (t >= off) ? lx[t - off] : 0;
        __syncthreads();
        lx[t] += y;
        __syncthreads();
    }
    const int incl = lx[t];
    const int row = r0 + t;
    if (row < NN) endv[row] = (int)s0 + incl;
    __syncthreads();
    lh[t] = (int)s0 + incl - myc;     // global exclusive offset (bump)
    __syncthreads();

    for (size_t e = s0 + t; e < s1; e += 256) {
        uint2 ed = ebin[e];
        int pos = atomicAdd(&lh[(ed.x >> 16) & 255], 1);
        epack[pos] = make_uint2(ed.x & 0xffffu, ed.y);
    }
}

// ============ K3: gather, wave per row, 4 edge slots x 16 lanes ============
__global__ __launch_bounds__(256) void gather_kernel(const unsigned short* __restrict__ h,
                                                     const int* __restrict__ end,
                                                     const unsigned int* __restrict__ epack,
                                                     const float* __restrict__ b,
                                                     float* __restrict__ out) {
    const int row  = blockIdx.x * 4 + (threadIdx.x >> 6);
    const int lane = threadIdx.x & 63;
    const int slot = lane >> 4;
    const int sub  = lane & 15;
    const int begin = (row & 255) ? end[row - 1] : (row >> BK_SHIFT) * ECAP;
    const int e1 = end[row];

    float acc[8] = {0.f, 0.f, 0.f, 0.f, 0.f, 0.f, 0.f, 0.f};
    const unsigned short* hp = h + sub * 8;

#define BODY(EE) do {                                                          \
        uint32x2 cv = __builtin_nontemporal_load(                              \
            (const uint32x2*)(epack + (size_t)(EE) * 2));                      \
        float v = __uint_as_float(cv.y);                                       \
        uint4 hv = *(const uint4*)(hp + (size_t)cv.x * DD);                    \
        unsigned int uu;                                                       \
        uu = hv.x;                                                             \
        acc[0] = fmaf(v, __uint_as_float(uu << 16),          acc[0]);          \
        acc[1] = fmaf(v, __uint_as_float(uu & 0xffff0000u),  acc[1]);          \
        uu = hv.y;                                                             \
        acc[2] = fmaf(v, __uint_as_float(uu << 16),          acc[2]);          \
        acc[3] = fmaf(v, __uint_as_float(uu & 0xffff0000u),  acc[3]);          \
        uu = hv.z;                                                             \
        acc[4] = fmaf(v, __uint_as_float(uu << 16),          acc[4]);          \
        acc[5] = fmaf(v, __uint_as_float(uu & 0xffff0000u),  acc[5]);          \
        uu = hv.w;                                                             \
        acc[6] = fmaf(v, __uint_as_float(uu << 16),          acc[6]);          \
        acc[7] = fmaf(v, __uint_as_float(uu & 0xffff0000u),  acc[7]);          \
    } while (0)

    int e = begin + slot;
    for (; e + 4 < e1; e += 8) { BODY(e); BODY(e + 4); }
    if (e < e1) BODY(e);
#undef BODY

#pragma unroll
    for (int i = 0; i < 8; ++i) {
        acc[i] += __shfl_xor(acc[i], 16);
        acc[i] += __shfl_xor(acc[i], 32);
    }

    if (slot == 0) {
        const float4* b4 = (const float4*)(b + sub * 8);
        float4 b0 = b4[0], b1 = b4[1];
        f32x4 o0, o1;
        o0.x = fmaxf(acc[0] + b0.x, 0.f);
        o0.y = fmaxf(acc[1] + b0.y, 0.f);
        o0.z = fmaxf(acc[2] + b0.z, 0.f);
        o0.w = fmaxf(acc[3] + b0.w, 0.f);
        o1.x = fmaxf(acc[4] + b1.x, 0.f);
        o1.y = fmaxf(acc[5] + b1.y, 0.f);
        o1.z = fmaxf(acc[6] + b1.z, 0.f);
        o1.w = fmaxf(acc[7] + b1.w, 0.f);
        f32x4* op = (f32x4*)(out + (size_t)row * DD + sub * 8);
        __builtin_nontemporal_store(o0, op);
        __builtin_nontemporal_store(o1, op + 1);
    }
}

// ============ Fallback (ws too small): atomic scatter path ============
__global__ __launch_bounds__(256) void scatter_kernel(const unsigned short* __restrict__ h,
                                                      const int* __restrict__ erow,
                                                      const int* __restrict__ ecol,
                                                      const float* __restrict__ eval,
                                                      float* __restrict__ out) {
    const int lane   = threadIdx.x & 63;
    const int wave   = (blockIdx.x * blockDim.x + threadIdx.x) >> 6;
    const int nwaves = (gridDim.x * blockDim.x) >> 6;
    for (int e = wave; e < NE; e += nwaves) {
        int   r = erow[e];
        int   c = ecol[e];
        float v = eval[e];
        unsigned int u = *(const unsigned int*)&h[(size_t)c * DD + lane * 2];
        float* dst = &out[(size_t)r * DD + lane * 2];
        unsafeAtomicAdd(dst,     __uint_as_float(u << 16) * v);
        unsafeAtomicAdd(dst + 1, __uint_as_float(u & 0xffff0000u) * v);
    }
}

__global__ __launch_bounds__(256) void epilogue_kernel(float* __restrict__ out,
                                                       const float* __restrict__ b) {
    const float4* b4 = (const float4*)b;
    const int total4 = NN * DD / 4;
    int i = blockIdx.x * blockDim.x + threadIdx.x;
    for (; i < total4; i += gridDim.x * blockDim.x) {
        float4 x = ((float4*)out)[i];
        float4 bb = b4[i & 31];
        x.x = fmaxf(x.x + bb.x, 0.0f);
        x.y = fmaxf(x.y + bb.y, 0.0f);
        x.z = fmaxf(x.z + bb.z, 0.0f);
        x.w = fmaxf(x.w + bb.w, 0.0f);
        ((float4*)out)[i] = x;
    }
}

extern "C" void kernel_launch(void* const* d_in, const int* in_sizes, int n_in,
                              void* d_out, int out_size, void* d_ws, size_t ws_size,
                              hipStream_t stream) {
    const float* seq  = (const float*)d_in[0];
    const float* W    = (const float*)d_in[1];
    const float* b    = (const float*)d_in[2];
    const int*   erow = (const int*)d_in[3];
    const int*   ecol = (const int*)d_in[4];
    const float* eval = (const float*)d_in[5];
    float* out = (float*)d_out;

    float* wsf = (float*)d_ws;
    unsigned short* h = (unsigned short*)(wsf + OFF_H);
    uint2* ebin  = (uint2*)(wsf + OFF_EBIN);
    uint2* epack = (uint2*)(wsf + OFF_EPACK);
    int*   endv  = (int*)(wsf + OFF_END);
    int*   gcur  = (int*)(wsf + OFF_CUR);

    if (ws_size >= (size_t)WS_FULL_FLOATS * sizeof(float)) {
        hipMemsetAsync(gcur, 0, NBUCK * sizeof(int), stream);
        k1_gemm_scatter<<<NGB + NCHUNK, 256, 0, stream>>>(seq, W, h, erow, ecol,
                                                          eval, gcur, ebin);
        csr_fill<<<NBUCK, 256, 0, stream>>>(ebin, gcur, endv, epack);
        gather_kernel<<<NN / 4, 256, 0, stream>>>(h, endv, (const unsigned int*)epack, b, out);
    } else {
        k1_gemm_scatter<<<NGB, 256, 0, stream>>>(seq, W, h, erow, ecol, eval,
                                                 gcur, ebin);
        hipMemsetAsync(out, 0, (size_t)out_size * sizeof(float), stream);
        scatter_kernel<<<4096, 256, 0, stream>>>(h, erow, ecol, eval, out);
        epilogue_kernel<<<2048, 256, 0, stream>>>(out, b);
    }
}

// Round 9
// 85.328 us; speedup vs baseline: 10.3213x; 1.0443x over previous
//
#include <hip/hip_runtime.h>

#define NN 50000
#define NE 800000
#define DD 128

#define BK_SHIFT 8                 // bucket = row >> 8 (256 rows per bucket)
#define NBUCK 196
#define CHUNK 4096
#define NCHUNK 196                 // ceil(800000/4096)
#define NGB 782                    // ceil(50000/64) gemm blocks
#define ECAP 8192                  // entries per bucket region (mean 4096, sigma 64)

// ---------------- ws layout (float units) ----------------
#define OFF_H      0               // NN*DD bf16 = 3,200,000 floats
#define OFF_EBIN   3200000         // NBUCK*ECAP uint2 = 3,211,264 floats
#define OFF_EPACK  6411264         // NBUCK*ECAP uint2
#define OFF_END    9622528         // NN ints
#define OFF_CUR    9672528         // NBUCK ints
#define WS_FULL_FLOATS 9672724     // ~38.7 MB

typedef short short8 __attribute__((ext_vector_type(8)));
typedef float f32x4 __attribute__((ext_vector_type(4)));
typedef unsigned int uint32x2 __attribute__((ext_vector_type(2)));

static __device__ __forceinline__ unsigned int f2bf(float x) {
    unsigned int u = __float_as_uint(x);
    return (u + 0x7fffu + ((u >> 16) & 1u)) >> 16;  // RNE
}

// ============ K1: bucket-scatter (blocks 0..NCHUNK-1, runs FIRST) ||
//               MFMA GEMM (blocks NCHUNK..NCHUNK+NGB-1) =======
// Scatter first: its LDS-atomic/random-write latency hides under the gemm
// blocks co-resident on each CU; the kernel tail is dense gemm work.
__global__ __launch_bounds__(256) void k1_gemm_scatter(
        const float* __restrict__ seq, const float* __restrict__ W,
        unsigned short* __restrict__ h,
        const int* __restrict__ erow, const int* __restrict__ ecol,
        const float* __restrict__ eval,
        int* __restrict__ gcur, uint2* __restrict__ ebin) {
    __shared__ uint4 lds4[3072];           // 48 KB
    char* lds = (char*)lds4;
    const int t = threadIdx.x;

    if (blockIdx.x < NCHUNK) {
        // ---- scatter path: LDS hist -> global bump-reserve -> run writes ----
        int* lh = (int*)lds4;              // [NBUCK] count, then cursor
        const int chunk = blockIdx.x;
        for (int i = t; i < NBUCK; i += 256) lh[i] = 0;
        __syncthreads();
        const int e0 = chunk * CHUNK;
        for (int i = t; i < CHUNK; i += 256) {
            int e = e0 + i;
            if (e < NE) atomicAdd(&lh[erow[e] >> BK_SHIFT], 1);
        }
        __syncthreads();
        for (int i = t; i < NBUCK; i += 256) {
            int c = lh[i];
            lh[i] = c ? atomicAdd(&gcur[i], c) : 0;   // count -> bucket-local base
        }
        __syncthreads();
        for (int i = t; i < CHUNK; i += 256) {
            int e = e0 + i;
            if (e < NE) {
                int r = erow[e], c = ecol[e];
                unsigned int vb = __float_as_uint(eval[e]);
                int k = r >> BK_SHIFT;
                int pos = atomicAdd(&lh[k], 1);
                if (pos < ECAP)
                    ebin[(size_t)k * ECAP + pos] =
                        make_uint2(((unsigned)r << 16) | (unsigned)c, vb);
            }
        }
        return;
    }

    // ---- GEMM path: h[n][o] = sum_k seq[n][k]*W[o][k], bf16-in fp32-acc ----
    const int base = (blockIdx.x - NCHUNK) * 64;
#define BS_OFF 16384

    // stage Bs: W[o][k] fp32 -> bf16, swizzled. thread: o=t>>1, 64 k's.
    {
        const int o = t >> 1, ksb = (t & 1) * 64;
        const float4* Wr = (const float4*)(W + o * 128 + ksb);
#pragma unroll
        for (int i = 0; i < 16; i += 2) {
            float4 x = Wr[i], y = Wr[i + 1];
            uint4 p;
            p.x = f2bf(x.x) | (f2bf(x.y) << 16);
            p.y = f2bf(x.z) | (f2bf(x.w) << 16);
            p.z = f2bf(y.x) | (f2bf(y.y) << 16);
            p.w = f2bf(y.z) | (f2bf(y.w) << 16);
            int byte = o * 256 + (ksb + i * 4) * 2;
            *(uint4*)(lds + BS_OFF + (byte ^ ((o & 7) << 4))) = p;
        }
    }
    // stage As: seq rows [base..base+64) fp32 -> bf16, swizzled.
    {
        const int row = t >> 2, n = base + row;
        const int c0 = (t & 3) * 4;
        const float4* Sr = (const float4*)(seq + (size_t)n * 128);
        const bool ok = (n < NN);
#pragma unroll
        for (int i = 0; i < 4; ++i) {
            int cc = c0 + i;
            float4 x = ok ? Sr[cc * 2]     : make_float4(0.f, 0.f, 0.f, 0.f);
            float4 y = ok ? Sr[cc * 2 + 1] : make_float4(0.f, 0.f, 0.f, 0.f);
            uint4 p;
            p.x = f2bf(x.x) | (f2bf(x.y) << 16);
            p.y = f2bf(x.z) | (f2bf(x.w) << 16);
            p.z = f2bf(y.x) | (f2bf(y.y) << 16);
            p.w = f2bf(y.z) | (f2bf(y.w) << 16);
            int byte = row * 256 + cc * 16;
            *(uint4*)(lds + (byte ^ ((row & 7) << 4))) = p;
        }
    }
    __syncthreads();

    const int l = t & 63, wv = t >> 6;
    const int lr = l & 15, kg = l >> 4;
    const int arow = wv * 16 + lr;
    f32x4 acc[8] = {};

#pragma unroll
    for (int ks = 0; ks < 4; ++ks) {
        const int kbyte = ks * 64 + kg * 16;
        short8 av = *(short8*)(lds + ((arow * 256 + kbyte) ^ ((arow & 7) << 4)));
#pragma unroll
        for (int c = 0; c < 8; ++c) {
            const int o = c * 16 + lr;
            short8 bv = *(short8*)(lds + BS_OFF +
                                   ((o * 256 + kbyte) ^ ((o & 7) << 4)));
            acc[c] = __builtin_amdgcn_mfma_f32_16x16x32_bf16(av, bv, acc[c], 0, 0, 0);
        }
    }

#pragma unroll
    for (int c = 0; c < 8; ++c) {
#pragma unroll
        for (int r = 0; r < 4; ++r) {
            int n = base + wv * 16 + kg * 4 + r;
            if (n < NN)
                h[(size_t)n * DD + c * 16 + lr] = (unsigned short)f2bf(acc[c][r]);
        }
    }
}

// ============ K2: per-bucket CSR build + payload fill ============
__global__ __launch_bounds__(256) void csr_fill(const uint2* __restrict__ ebin,
                                                const int* __restrict__ gcur,
                                                int* __restrict__ endv,
                                                uint2* __restrict__ epack) {
    __shared__ int lh[256];
    __shared__ int lx[256];
    const int k = blockIdx.x;
    const int t = threadIdx.x;
    const size_t s0 = (size_t)k * ECAP;
    int cnt = gcur[k];
    if (cnt > ECAP) cnt = ECAP;
    const size_t s1 = s0 + cnt;
    const int r0 = k << BK_SHIFT;

    lh[t] = 0;
    __syncthreads();
    for (size_t e = s0 + t; e < s1; e += 256)
        atomicAdd(&lh[(ebin[e].x >> 16) & 255], 1);
    __syncthreads();

    const int myc = lh[t];
    lx[t] = myc;
    __syncthreads();
    for (int off = 1; off < 256; off <<= 1) {
        int y = (t >= off) ? lx[t - off] : 0;
        __syncthreads();
        lx[t] += y;
        __syncthreads();
    }
    const int incl = lx[t];
    const int row = r0 + t;
    if (row < NN) endv[row] = (int)s0 + incl;
    __syncthreads();
    lh[t] = (int)s0 + incl - myc;     // global exclusive offset (bump)
    __syncthreads();

    for (size_t e = s0 + t; e < s1; e += 256) {
        uint2 ed = ebin[e];
        int pos = atomicAdd(&lh[(ed.x >> 16) & 255], 1);
        epack[pos] = make_uint2(ed.x & 0xffffu, ed.y);
    }
}

// ============ K3: gather, wave per row, 4 edge slots x 16 lanes ============
__global__ __launch_bounds__(256) void gather_kernel(const unsigned short* __restrict__ h,
                                                     const int* __restrict__ end,
                                                     const unsigned int* __restrict__ epack,
                                                     const float* __restrict__ b,
                                                     float* __restrict__ out) {
    const int row  = blockIdx.x * 4 + (threadIdx.x >> 6);
    const int lane = threadIdx.x & 63;
    const int slot = lane >> 4;
    const int sub  = lane & 15;
    const int begin = (row & 255) ? end[row - 1] : (row >> BK_SHIFT) * ECAP;
    const int e1 = end[row];

    float acc[8] = {0.f, 0.f, 0.f, 0.f, 0.f, 0.f, 0.f, 0.f};
    const unsigned short* hp = h + sub * 8;

#define BODY(EE) do {                                                          \
        uint32x2 cv = __builtin_nontemporal_load(                              \
            (const uint32x2*)(epack + (size_t)(EE) * 2));                      \
        float v = __uint_as_float(cv.y);                                       \
        uint4 hv = *(const uint4*)(hp + (size_t)cv.x * DD);                    \
        unsigned int uu;                                                       \
        uu = hv.x;                                                             \
        acc[0] = fmaf(v, __uint_as_float(uu << 16),          acc[0]);          \
        acc[1] = fmaf(v, __uint_as_float(uu & 0xffff0000u),  acc[1]);          \
        uu = hv.y;                                                             \
        acc[2] = fmaf(v, __uint_as_float(uu << 16),          acc[2]);          \
        acc[3] = fmaf(v, __uint_as_float(uu & 0xffff0000u),  acc[3]);          \
        uu = hv.z;                                                             \
        acc[4] = fmaf(v, __uint_as_float(uu << 16),          acc[4]);          \
        acc[5] = fmaf(v, __uint_as_float(uu & 0xffff0000u),  acc[5]);          \
        uu = hv.w;                                                             \
        acc[6] = fmaf(v, __uint_as_float(uu << 16),          acc[6]);          \
        acc[7] = fmaf(v, __uint_as_float(uu & 0xffff0000u),  acc[7]);          \
    } while (0)

    int e = begin + slot;
    for (; e + 4 < e1; e += 8) { BODY(e); BODY(e + 4); }
    if (e < e1) BODY(e);
#undef BODY

#pragma unroll
    for (int i = 0; i < 8; ++i) {
        acc[i] += __shfl_xor(acc[i], 16);
        acc[i] += __shfl_xor(acc[i], 32);
    }

    if (slot == 0) {
        const float4* b4 = (const float4*)(b + sub * 8);
        float4 b0 = b4[0], b1 = b4[1];
        f32x4 o0, o1;
        o0.x = fmaxf(acc[0] + b0.x, 0.f);
        o0.y = fmaxf(acc[1] + b0.y, 0.f);
        o0.z = fmaxf(acc[2] + b0.z, 0.f);
        o0.w = fmaxf(acc[3] + b0.w, 0.f);
        o1.x = fmaxf(acc[4] + b1.x, 0.f);
        o1.y = fmaxf(acc[5] + b1.y, 0.f);
        o1.z = fmaxf(acc[6] + b1.z, 0.f);
        o1.w = fmaxf(acc[7] + b1.w, 0.f);
        f32x4* op = (f32x4*)(out + (size_t)row * DD + sub * 8);
        __builtin_nontemporal_store(o0, op);
        __builtin_nontemporal_store(o1, op + 1);
    }
}

// ============ Fallback (ws too small): atomic scatter path ============
__global__ __launch_bounds__(256) void scatter_kernel(const unsigned short* __restrict__ h,
                                                      const int* __restrict__ erow,
                                                      const int* __restrict__ ecol,
                                                      const float* __restrict__ eval,
                                                      float* __restrict__ out) {
    const int lane   = threadIdx.x & 63;
    const int wave   = (blockIdx.x * blockDim.x + threadIdx.x) >> 6;
    const int nwaves = (gridDim.x * blockDim.x) >> 6;
    for (int e = wave; e < NE; e += nwaves) {
        int   r = erow[e];
        int   c = ecol[e];
        float v = eval[e];
        unsigned int u = *(const unsigned int*)&h[(size_t)c * DD + lane * 2];
        float* dst = &out[(size_t)r * DD + lane * 2];
        unsafeAtomicAdd(dst,     __uint_as_float(u << 16) * v);
        unsafeAtomicAdd(dst + 1, __uint_as_float(u & 0xffff0000u) * v);
    }
}

__global__ __launch_bounds__(256) void epilogue_kernel(float* __restrict__ out,
                                                       const float* __restrict__ b) {
    const float4* b4 = (const float4*)b;
    const int total4 = NN * DD / 4;
    int i = blockIdx.x * blockDim.x + threadIdx.x;
    for (; i < total4; i += gridDim.x * blockDim.x) {
        float4 x = ((float4*)out)[i];
        float4 bb = b4[i & 31];
        x.x = fmaxf(x.x + bb.x, 0.0f);
        x.y = fmaxf(x.y + bb.y, 0.0f);
        x.z = fmaxf(x.z + bb.z, 0.0f);
        x.w = fmaxf(x.w + bb.w, 0.0f);
        ((float4*)out)[i] = x;
    }
}

extern "C" void kernel_launch(void* const* d_in, const int* in_sizes, int n_in,
                              void* d_out, int out_size, void* d_ws, size_t ws_size,
                              hipStream_t stream) {
    const float* seq  = (const float*)d_in[0];
    const float* W    = (const float*)d_in[1];
    const float* b    = (const float*)d_in[2];
    const int*   erow = (const int*)d_in[3];
    const int*   ecol = (const int*)d_in[4];
    const float* eval = (const float*)d_in[5];
    float* out = (float*)d_out;

    float* wsf = (float*)d_ws;
    unsigned short* h = (unsigned short*)(wsf + OFF_H);
    uint2* ebin  = (uint2*)(wsf + OFF_EBIN);
    uint2* epack = (uint2*)(wsf + OFF_EPACK);
    int*   endv  = (int*)(wsf + OFF_END);
    int*   gcur  = (int*)(wsf + OFF_CUR);

    if (ws_size >= (size_t)WS_FULL_FLOATS * sizeof(float)) {
        hipMemsetAsync(gcur, 0, NBUCK * sizeof(int), stream);
        k1_gemm_scatter<<<NGB + NCHUNK, 256, 0, stream>>>(seq, W, h, erow, ecol,
                                                          eval, gcur, ebin);
        csr_fill<<<NBUCK, 256, 0, stream>>>(ebin, gcur, endv, epack);
        gather_kernel<<<NN / 4, 256, 0, stream>>>(h, endv, (const unsigned int*)epack, b, out);
    } else {
        k1_gemm_scatter<<<NGB + NCHUNK, 256, 0, stream>>>(seq, W, h, erow, ecol,
                                                          eval, gcur, ebin);
        hipMemsetAsync(out, 0, (size_t)out_size * sizeof(float), stream);
        scatter_kernel<<<4096, 256, 0, stream>>>(h, erow, ecol, eval, out);
        epilogue_kernel<<<2048, 256, 0, stream>>>(out, b);
    }
}